// Round 1
// baseline (211.252 us; speedup 1.0000x reference)
//
#include <hip/hip_runtime.h>

// Gaunt tensor product via exact collapse of the S2-grid path to a
// 25x9x9 Gaunt tensor G computed on-device from Y_in/Y_out/qw.
//
// Shapes:
//  x1,x2 : [N=2048][MUL=64][2][9]  f32
//  W1,W2 : [3][3][64][64]          f32   (branch, l, mul, C)
//  Wout  : [3][5][64][64]          f32   (branch, l, C, C)
//  Y_in  : [9][780], Y_out: [25][780], qw: [20]
//  out   : [N][3][C=64][25]        f32

#define NN 2048

__host__ __device__ constexpr int l_of9(int i)  { return i < 1 ? 0 : (i < 4 ? 1 : 2); }
__host__ __device__ constexpr int l_of25(int k) { return k < 1 ? 0 : (k < 4 ? 1 : (k < 9 ? 2 : (k < 16 ? 3 : 4))); }
__host__ __device__ constexpr int iabs_(int v)  { return v < 0 ? -v : v; }

// Compile-time superset of nonzero real-Gaunt entries:
// triangle rule, (l1+l2+l3) even, |m3| in {|m1+m2|, |m1-m2|}.
__host__ __device__ constexpr bool gmask(int k, int i, int j) {
    const int l3 = l_of25(k), m3 = k - l3 * l3 - l3;
    const int l1 = l_of9(i),  m1 = i - l1 * l1 - l1;
    const int l2 = l_of9(j),  m2 = j - l2 * l2 - l2;
    if (((l1 + l2 + l3) & 1) != 0) return false;
    if (l3 > l1 + l2 || l3 < iabs_(l1 - l2)) return false;
    const int am3 = iabs_(m3);
    return (am3 == iabs_(m1 + m2)) || (am3 == iabs_(m1 - m2));
}

// ---------------------------------------------------------------------------
// Kernel A: G[k][i][j] = sum_p qw[p/39] * Y_out[k,p] * Y_in[i,p] * Y_in[j,p]
// 25 blocks (one per k), 256 threads. p-range split 3 ways per (i,j) pair.
// ---------------------------------------------------------------------------
__global__ __launch_bounds__(256) void gaunt_G_kernel(
    const float* __restrict__ Y_in, const float* __restrict__ Y_out,
    const float* __restrict__ qw, float* __restrict__ G)
{
    const int k = blockIdx.x;      // 0..24
    const int t = threadIdx.x;     // 0..255

    __shared__ float yis[9 * 780];
    __shared__ float yos[780];
    __shared__ float qf[780];
    __shared__ float psum[81 * 3];

    for (int idx = t; idx < 9 * 780; idx += 256) yis[idx] = Y_in[idx];
    for (int idx = t; idx < 780; idx += 256) {
        yos[idx] = Y_out[k * 780 + idx];
        qf[idx]  = qw[idx / 39];
    }
    __syncthreads();

    if (t < 243) {
        const int r = t / 3;        // pair index 0..80
        const int s = t % 3;        // p-slice
        const int i = r / 9, j = r % 9;
        const float* yi = &yis[i * 780];
        const float* yj = &yis[j * 780];
        const int p0 = s * 260;
        float acc = 0.f;
        for (int p = p0; p < p0 + 260; ++p) {
            acc = fmaf(qf[p] * yos[p], yi[p] * yj[p], acc);
        }
        psum[r * 3 + s] = acc;
    }
    __syncthreads();

    if (t < 81) {
        G[k * 81 + t] = psum[t * 3 + 0] + psum[t * 3 + 1] + psum[t * 3 + 2];
    }
}

// ---------------------------------------------------------------------------
// Kernel B: main fused kernel. One block per n; 192 threads = 3 waves.
// wave = branch b, lane = output channel c.
// ---------------------------------------------------------------------------
__global__ __launch_bounds__(192) void gaunt_main_kernel(
    const float* __restrict__ x1, const float* __restrict__ x2,
    const float* __restrict__ W1, const float* __restrict__ W2,
    const float* __restrict__ Wout, const float* __restrict__ G,
    float* __restrict__ out)
{
    const int n = blockIdx.x;
    const int t = threadIdx.x;
    const int b = t >> 6;    // branch 0..2
    const int c = t & 63;    // channel 0..63

    __shared__ float x1s[64 * 18];   // [m][parity][i] = m*18 + p*9 + i
    __shared__ float x2s[64 * 18];
    __shared__ float Gs[2025];
    __shared__ float cosh_[3 * 64 * 25];  // co[b][d][k]

    // ---- Phase 0: stage x1[n], x2[n], G into LDS (coalesced) ----
    {
        const float* x1n = x1 + (size_t)n * 1152;
        const float* x2n = x2 + (size_t)n * 1152;
        for (int idx = t; idx < 1152; idx += 192) x1s[idx] = x1n[idx];
        for (int idx = t; idx < 1152; idx += 192) x2s[idx] = x2n[idx];
        for (int idx = t; idx < 2025; idx += 192) Gs[idx] = G[idx];
    }
    __syncthreads();

    // ---- Phase 1: projection  c1[i] = 0.125 * sum_m x1[m,pidx,i]*W1[b,l,m,c]
    float c1r[9], c2r[9];
#pragma unroll
    for (int i = 0; i < 9; ++i) { c1r[i] = 0.f; c2r[i] = 0.f; }

    const int e1 = (b == 2) ? 1 : 0;   // p1 = -1 only on branch 2
    const int e2 = (b == 1) ? 1 : 0;   // p2 = -1 only on branch 1
    const float* W1b = W1 + b * 3 * 4096;
    const float* W2b = W2 + b * 3 * 4096;

#pragma unroll
    for (int l = 0; l < 3; ++l) {
        const int p1 = (l & 1) ^ e1;
        const int p2 = (l & 1) ^ e2;
        const int xo1 = p1 * 9 + l * l;
        const int xo2 = p2 * 9 + l * l;
        const float* W1l = W1b + l * 4096 + c;
        const float* W2l = W2b + l * 4096 + c;
        for (int m = 0; m < 64; ++m) {
            const float w1 = W1l[m * 64];
            const float w2 = W2l[m * 64];
            const float* xr1 = &x1s[m * 18 + xo1];
            const float* xr2 = &x2s[m * 18 + xo2];
#pragma unroll
            for (int ii = 0; ii < 2 * l + 1; ++ii) {
                c1r[l * l + ii] = fmaf(xr1[ii], w1, c1r[l * l + ii]);
                c2r[l * l + ii] = fmaf(xr2[ii], w2, c2r[l * l + ii]);
            }
        }
    }
#pragma unroll
    for (int i = 0; i < 9; ++i) { c1r[i] *= 0.125f; c2r[i] *= 0.125f; }

    // ---- Phase 2: masked Gaunt contraction  co[k] = sum_ij G[k,i,j] c1_i c2_j
    float co[25];
#pragma unroll
    for (int k = 0; k < 25; ++k) co[k] = 0.f;

#pragma unroll
    for (int i = 0; i < 9; ++i) {
#pragma unroll
        for (int j = 0; j < 9; ++j) {
            const float p = c1r[i] * c2r[j];
#pragma unroll
            for (int k = 0; k < 25; ++k) {
                if (gmask(k, i, j)) {
                    co[k] = fmaf(Gs[k * 81 + i * 9 + j], p, co[k]);
                }
            }
        }
    }

    // ---- Phase 3: share co across lanes (need all d for output mixing) ----
#pragma unroll
    for (int k = 0; k < 25; ++k) cosh_[(b * 64 + c) * 25 + k] = co[k];
    __syncthreads();

    // ---- Phase 4: output linear  out[n,b,c,k] = 0.125 * sum_d co[b,d,k]*Wout[b,l(k),d,c]
    const float* Woutb = Wout + b * 5 * 4096 + c;
    float* outn = out + ((size_t)n * 3 + b) * 64 * 25 + (size_t)c * 25;

#pragma unroll
    for (int l3 = 0; l3 < 5; ++l3) {
        const int k0 = l3 * l3;
        const int nk = 2 * l3 + 1;
        const float* Wl = Woutb + l3 * 4096;
        float acc[9];
#pragma unroll
        for (int kk = 0; kk < 9; ++kk) acc[kk] = 0.f;
        for (int d = 0; d < 64; ++d) {
            const float w = Wl[d * 64];
            const float* cr = &cosh_[(b * 64 + d) * 25 + k0];
#pragma unroll
            for (int kk = 0; kk < nk; ++kk) acc[kk] = fmaf(cr[kk], w, acc[kk]);
        }
#pragma unroll
        for (int kk = 0; kk < nk; ++kk) outn[k0 + kk] = acc[kk] * 0.125f;
    }
}

extern "C" void kernel_launch(void* const* d_in, const int* in_sizes, int n_in,
                              void* d_out, int out_size, void* d_ws, size_t ws_size,
                              hipStream_t stream) {
    const float* x1    = (const float*)d_in[0];
    const float* x2    = (const float*)d_in[1];
    const float* W1    = (const float*)d_in[2];
    const float* W2    = (const float*)d_in[3];
    const float* Wout  = (const float*)d_in[4];
    const float* Y_in  = (const float*)d_in[5];
    const float* Y_out = (const float*)d_in[6];
    const float* qw    = (const float*)d_in[7];
    float* outp = (float*)d_out;
    float* G    = (float*)d_ws;   // 2025 floats

    gaunt_G_kernel<<<25, 256, 0, stream>>>(Y_in, Y_out, qw, G);
    gaunt_main_kernel<<<NN, 192, 0, stream>>>(x1, x2, W1, W2, Wout, G, outp);
}